// Round 2
// baseline (209.653 us; speedup 1.0000x reference)
//
#include <hip/hip_runtime.h>
#include <math.h>

// Problem constants (fixed by setup_inputs): x is (8,1024,1024,2) fp32, k=61
#define NB 8
#define HH 1024
#define WW 1024
#define RAD 30
#define KS 61
#define ROWSZ 2048             /* floats per row (1024 px x 2 ch) */
#define IMGSZ (HH * ROWSZ)
#define STR2 1024              /* float2 (or pixel) stride per row */
#define NCOL2 (NB * STR2)      /* 8192 float2 columns */
#define VSEGH 64
#define VNSEG (HH / VSEGH)     /* 16 */
#define EPSV 1e-7f
#define SCALEV (1.0f / (float)(KS * KS * 2))
#define PDW (WW + WW / 8)
#define PD(i) ((i) + ((i) >> 3))

// ---- bf16 pack/unpack (manual, round-to-nearest-even) ----------------------
__device__ __forceinline__ unsigned bf16_rn(float f) {
    unsigned u = __float_as_uint(f);
    return (u + 0x7FFFu + ((u >> 16) & 1u)) >> 16;
}
__device__ __forceinline__ unsigned pk2(float a, float b) {
    return bf16_rn(a) | (bf16_rn(b) << 16);
}
__device__ __forceinline__ float2 up2(unsigned u) {
    return make_float2(__uint_as_float(u << 16),
                       __uint_as_float(u & 0xFFFF0000u));
}

__device__ __forceinline__ float2 f2add(float2 a, float2 b) {
    return make_float2(a.x + b.x, a.y + b.y);
}
__device__ __forceinline__ float2 f2sub(float2 a, float2 b) {
    return make_float2(a.x - b.x, a.y - b.y);
}

// ---------------------------------------------------------------------------
// K1: vertical 61-tap box-sum of x -> V1 (bf16-packed). float2 columns,
// VSEGH=64 rows/seg, 512 blocks. (unchanged from prior verified version)
__global__ __launch_bounds__(256, 2) void vbox_kernel(const float* __restrict__ in,
                                                      unsigned* __restrict__ out) {
    int tid = blockIdx.x * 256 + threadIdx.x;
    int col = tid & (NCOL2 - 1);
    int seg = tid >> 13;
    int n = col >> 10;
    int w2 = col & (STR2 - 1);
    const float2* ip = (const float2*)(in + (size_t)n * IMGSZ) + w2;
    unsigned* op = out + (size_t)n * (IMGSZ / 2) + w2;
    int h0 = seg * VSEGH;
    float2 S = make_float2(0.f, 0.f);
    int lo = h0 - RAD; if (lo < 0) lo = 0;
    int h = lo;
    for (; h + 8 <= h0 + RAD; h += 8) {
        float2 W[8];
        #pragma unroll
        for (int i = 0; i < 8; ++i) W[i] = ip[(h + i) * STR2];
        __builtin_amdgcn_sched_barrier(0);
        #pragma unroll
        for (int i = 0; i < 8; ++i) S = f2add(S, W[i]);
    }
    for (; h < h0 + RAD; ++h) S = f2add(S, ip[h * STR2]);

    if (seg != 0 && seg != VNSEG - 1) {
        const float2* lp = ip + (h0 + RAD) * STR2;
        const float2* tp = ip + (h0 - RAD) * STR2;
        unsigned* opp = op + (size_t)h0 * STR2;
        for (int r = 0; r < VSEGH; r += 8) {
            float2 L[8], T[8];
            #pragma unroll
            for (int i = 0; i < 8; ++i) L[i] = lp[(r + i) * STR2];
            #pragma unroll
            for (int i = 0; i < 8; ++i) T[i] = tp[(r + i) * STR2];
            __builtin_amdgcn_sched_barrier(0);
            #pragma unroll
            for (int i = 0; i < 8; ++i) {
                S = f2add(S, L[i]);
                opp[(r + i) * STR2] = pk2(S.x, S.y);
                S = f2sub(S, T[i]);
            }
        }
    } else {
        const float2 Z = make_float2(0.f, 0.f);
        for (int ho = h0; ho < h0 + VSEGH; ho += 4) {
            float2 a[4], b[4];
            #pragma unroll
            for (int i = 0; i < 4; ++i) {
                int ha = ho + i + RAD;
                a[i] = (ha < HH) ? ip[ha * STR2] : Z;
            }
            #pragma unroll
            for (int i = 0; i < 4; ++i) {
                int hb = ho + i - RAD;
                b[i] = (hb >= 0) ? ip[hb * STR2] : Z;
            }
            #pragma unroll
            for (int i = 0; i < 4; ++i) {
                S = f2add(S, a[i]);
                op[(size_t)(ho + i) * STR2] = pk2(S.x, S.y);
                S = f2sub(S, b[i]);
            }
        }
    }
}

__device__ inline float wave_incl_scan(float v) {
    int lane = threadIdx.x & 63;
    #pragma unroll
    for (int d = 1; d < 64; d <<= 1) {
        float o = __shfl_up(v, d, 64);
        if (lane >= d) v += o;
    }
    return v;
}

// ---------------------------------------------------------------------------
// K2': fused middle kernel, one block per row.
//   phase 1: prefix-scan V1 row -> horizontal box -> m; out = x - m (fp32)
//   phase 2: prefix-scan out and out^2 rows (still in LDS) -> 61-tap horizontal
//            box sums, written INTERLEAVED as uint2{h1,h2} per pixel (bf16x2 each).
// Eliminates the old vbox2 kernel's 64 MB re-read of `out`.
__global__ __launch_bounds__(256) void hmid_kernel(const unsigned* __restrict__ vsum,
                                                   const float* __restrict__ x,
                                                   float* __restrict__ out,
                                                   uint2* __restrict__ hig) {
    __shared__ float ch[2][PDW];     // V1 per-channel prefix
    __shared__ float s4[4][PDW];     // [0..1]=out ch0/1, [2..3]=out^2 ch0/1
    __shared__ float wtot[4];
    int t = threadIdx.x;
    size_t g = (size_t)blockIdx.x * ROWSZ;
    const uint4* vrow = (const uint4*)(vsum + (size_t)blockIdx.x * STR2);
    uint4 u = vrow[t];   // 4 pixels x 2 ch
    {
        float2 p0 = up2(u.x), p1 = up2(u.y), p2 = up2(u.z), p3 = up2(u.w);
        int w = 4 * t;
        ch[0][PD(w + 0)] = p0.x; ch[1][PD(w + 0)] = p0.y;
        ch[0][PD(w + 1)] = p1.x; ch[1][PD(w + 1)] = p1.y;
        ch[0][PD(w + 2)] = p2.x; ch[1][PD(w + 2)] = p2.y;
        ch[0][PD(w + 3)] = p3.x; ch[1][PD(w + 3)] = p3.y;
    }
    __syncthreads();
    // prefix: 2 waves per channel, per-thread chunk of 8
    {
        int c = t >> 7, j = t & 127, base = j * 8;
        float v[8]; float run = 0.f;
        #pragma unroll
        for (int i = 0; i < 8; ++i) { run += ch[c][PD(base + i)]; v[i] = run; }
        float incl = wave_incl_scan(run);
        int wid = t >> 6;
        if ((t & 63) == 63) wtot[wid] = incl;
        __syncthreads();
        float off = incl - run;
        if (wid & 1) off += wtot[wid - 1];
        #pragma unroll
        for (int i = 0; i < 8; ++i) ch[c][PD(base + i)] = off + v[i];
    }
    __syncthreads();
    const float4* xrow = (const float4*)(x + g);
    float4* orow = (float4*)(out + g);
    #pragma unroll
    for (int i = 0; i < 2; ++i) {
        int jj = t + 256 * i;
        int w0 = 2 * jj, w1 = 2 * jj + 1;
        int hi0 = w0 + RAD; if (hi0 > WW - 1) hi0 = WW - 1;
        int hi1 = w1 + RAD; if (hi1 > WW - 1) hi1 = WW - 1;
        int lo0 = w0 - RAD - 1, lo1 = w1 - RAD - 1;
        float s00 = ch[0][PD(hi0)], s10 = ch[1][PD(hi0)];
        if (lo0 >= 0) { s00 -= ch[0][PD(lo0)]; s10 -= ch[1][PD(lo0)]; }
        float s01 = ch[0][PD(hi1)], s11 = ch[1][PD(hi1)];
        if (lo1 >= 0) { s01 -= ch[0][PD(lo1)]; s11 -= ch[1][PD(lo1)]; }
        float4 xv = xrow[jj];
        float4 o;
        o.x = xv.x - SCALEV * s00; o.y = xv.y - SCALEV * s10;
        o.z = xv.z - SCALEV * s01; o.w = xv.w - SCALEV * s11;
        orow[jj] = o;
        s4[0][PD(w0)] = o.x;       s4[1][PD(w0)] = o.y;
        s4[0][PD(w1)] = o.z;       s4[1][PD(w1)] = o.w;
        s4[2][PD(w0)] = o.x * o.x; s4[3][PD(w0)] = o.y * o.y;
        s4[2][PD(w1)] = o.z * o.z; s4[3][PD(w1)] = o.w * o.w;
    }
    __syncthreads();
    // prefix: 4 arrays, 1 wave each, chunk 16
    {
        int a = t >> 6, j = t & 63, base = j * 16;
        float v[16]; float run = 0.f;
        #pragma unroll
        for (int i = 0; i < 16; ++i) { run += s4[a][PD(base + i)]; v[i] = run; }
        float incl = wave_incl_scan(run);
        float off = incl - run;
        #pragma unroll
        for (int i = 0; i < 16; ++i) s4[a][PD(base + i)] = off + v[i];
    }
    __syncthreads();
    uint4* hirow = (uint4*)(hig + (size_t)blockIdx.x * STR2);
    #pragma unroll
    for (int i = 0; i < 2; ++i) {
        int jj = t + 256 * i;
        int w0 = 2 * jj, w1 = 2 * jj + 1;
        int hi0 = w0 + RAD; if (hi0 > WW - 1) hi0 = WW - 1;
        int hi1 = w1 + RAD; if (hi1 > WW - 1) hi1 = WW - 1;
        int lo0 = w0 - RAD - 1, lo1 = w1 - RAD - 1;
        float a00 = s4[0][PD(hi0)], a10 = s4[1][PD(hi0)];
        float q00 = s4[2][PD(hi0)], q10 = s4[3][PD(hi0)];
        if (lo0 >= 0) {
            a00 -= s4[0][PD(lo0)]; a10 -= s4[1][PD(lo0)];
            q00 -= s4[2][PD(lo0)]; q10 -= s4[3][PD(lo0)];
        }
        float a01 = s4[0][PD(hi1)], a11 = s4[1][PD(hi1)];
        float q01 = s4[2][PD(hi1)], q11 = s4[3][PD(hi1)];
        if (lo1 >= 0) {
            a01 -= s4[0][PD(lo1)]; a11 -= s4[1][PD(lo1)];
            q01 -= s4[2][PD(lo1)]; q11 -= s4[3][PD(lo1)];
        }
        // interleaved: per pixel uint2{ pk2(h1 ch0,ch1), pk2(h2 ch0,ch1) }
        hirow[jj] = make_uint4(pk2(a00, a10), pk2(q00, q10),
                               pk2(a01, a11), pk2(q01, q11));
    }
}

// ---------------------------------------------------------------------------
// K3': vertical 61-box of interleaved HI (bf16 in) + finalize
// y = out/(sqrt(var)+eps), in place on the out buffer.
__global__ __launch_bounds__(256, 2) void vfinal_kernel(const uint2* __restrict__ hi,
                                                        float* __restrict__ io) {
    int tid = blockIdx.x * 256 + threadIdx.x;
    int col = tid & (NCOL2 - 1);
    int seg = tid >> 13;
    int n = col >> 10;
    int w2 = col & (STR2 - 1);
    const uint2* pp = hi + (size_t)n * ((size_t)HH * STR2) + w2;
    float2* op = (float2*)(io + (size_t)n * IMGSZ) + w2;
    int h0 = seg * VSEGH;
    float2 S1 = make_float2(0.f, 0.f);
    float2 S2 = make_float2(0.f, 0.f);
    int lo = h0 - RAD; if (lo < 0) lo = 0;
    int h = lo;
    for (; h + 8 <= h0 + RAD; h += 8) {
        uint2 A[8];
        #pragma unroll
        for (int i = 0; i < 8; ++i) A[i] = pp[(h + i) * STR2];
        __builtin_amdgcn_sched_barrier(0);
        #pragma unroll
        for (int i = 0; i < 8; ++i) {
            S1 = f2add(S1, up2(A[i].x));
            S2 = f2add(S2, up2(A[i].y));
        }
    }
    for (; h < h0 + RAD; ++h) {
        uint2 v = pp[h * STR2];
        S1 = f2add(S1, up2(v.x));
        S2 = f2add(S2, up2(v.y));
    }

    if (seg != 0 && seg != VNSEG - 1) {
        const uint2* lp = pp + (h0 + RAD) * STR2;
        const uint2* tp = pp + (h0 - RAD) * STR2;
        float2* q = op + (size_t)h0 * STR2;
        for (int r = 0; r < VSEGH; r += 8) {
            uint2 L[8], T[8];
            float2 O[8];
            #pragma unroll
            for (int i = 0; i < 8; ++i) L[i] = lp[(r + i) * STR2];
            #pragma unroll
            for (int i = 0; i < 8; ++i) T[i] = tp[(r + i) * STR2];
            #pragma unroll
            for (int i = 0; i < 8; ++i) O[i] = q[(r + i) * STR2];
            __builtin_amdgcn_sched_barrier(0);
            #pragma unroll
            for (int i = 0; i < 8; ++i) {
                S1 = f2add(S1, up2(L[i].x));
                S2 = f2add(S2, up2(L[i].y));
                float c1x = SCALEV * S1.x, c1y = SCALEV * S1.y;
                float vx = fmaxf(SCALEV * S2.x - c1x * c1x, 0.f);
                float vy = fmaxf(SCALEV * S2.y - c1y * c1y, 0.f);
                float2 yv;
                yv.x = O[i].x / (sqrtf(vx) + EPSV);
                yv.y = O[i].y / (sqrtf(vy) + EPSV);
                q[(r + i) * STR2] = yv;
                S1 = f2sub(S1, up2(T[i].x));
                S2 = f2sub(S2, up2(T[i].y));
            }
        }
    } else {
        const uint2 Z2u = make_uint2(0u, 0u);
        for (int ho = h0; ho < h0 + VSEGH; ho += 4) {
            uint2 a[4], b[4];
            float2 O[4];
            #pragma unroll
            for (int i = 0; i < 4; ++i) {
                int ha = ho + i + RAD;
                a[i] = (ha < HH) ? pp[ha * STR2] : Z2u;
            }
            #pragma unroll
            for (int i = 0; i < 4; ++i) {
                int hb = ho + i - RAD;
                b[i] = (hb >= 0) ? pp[hb * STR2] : Z2u;
            }
            #pragma unroll
            for (int i = 0; i < 4; ++i) O[i] = op[(size_t)(ho + i) * STR2];
            #pragma unroll
            for (int i = 0; i < 4; ++i) {
                S1 = f2add(S1, up2(a[i].x));
                S2 = f2add(S2, up2(a[i].y));
                float c1x = SCALEV * S1.x, c1y = SCALEV * S1.y;
                float vx = fmaxf(SCALEV * S2.x - c1x * c1x, 0.f);
                float vy = fmaxf(SCALEV * S2.y - c1y * c1y, 0.f);
                float2 yv;
                yv.x = O[i].x / (sqrtf(vx) + EPSV);
                yv.y = O[i].y / (sqrtf(vy) + EPSV);
                op[(size_t)(ho + i) * STR2] = yv;
                S1 = f2sub(S1, up2(b[i].x));
                S2 = f2sub(S2, up2(b[i].y));
            }
        }
    }
}

extern "C" void kernel_launch(void* const* d_in, const int* in_sizes, int n_in,
                              void* d_out, int out_size, void* d_ws, size_t ws_size,
                              hipStream_t stream) {
    const float* x = (const float*)d_in[0];
    float* out = (float*)d_out;
    unsigned* V1 = (unsigned*)d_ws;                       // 32 MB bf16 vbox(x)
    uint2* HI = (uint2*)(V1 + (size_t)NB * IMGSZ / 2);    // 64 MB interleaved Hbox(out), Hbox(out^2)

    int vgrid = (NCOL2 * VNSEG) / 256;                    // 512 blocks
    vbox_kernel<<<vgrid, 256, 0, stream>>>(x, V1);
    hmid_kernel<<<NB * HH, 256, 0, stream>>>(V1, x, out, HI);
    vfinal_kernel<<<vgrid, 256, 0, stream>>>(HI, out);
}

// Round 4
// 208.918 us; speedup vs baseline: 1.0035x; 1.0035x over previous
//
#include <hip/hip_runtime.h>
#include <math.h>

// Problem constants (fixed by setup_inputs): x is (8,1024,1024,2) fp32, k=61
#define NB 8
#define HH 1024
#define WW 1024
#define RAD 30
#define KS 61
#define ROWSZ 2048             /* floats per row (1024 px x 2 ch) */
#define IMGSZ (HH * ROWSZ)
#define STR2 1024              /* float2 (or pixel) stride per row */
#define NCOL2 (NB * STR2)      /* 8192 float2 columns */
#define VSEGH 32               /* was 64: halved to double vertical-kernel occupancy */
#define VNSEG (HH / VSEGH)     /* 32 */
#define EPSV 1e-7f
#define SCALEV (1.0f / (float)(KS * KS * 2))
#define PDW (WW + WW / 8)
#define PD(i) ((i) + ((i) >> 3))

// ---- bf16 pack/unpack (manual, round-to-nearest-even) ----------------------
__device__ __forceinline__ unsigned bf16_rn(float f) {
    unsigned u = __float_as_uint(f);
    return (u + 0x7FFFu + ((u >> 16) & 1u)) >> 16;
}
__device__ __forceinline__ unsigned pk2(float a, float b) {
    return bf16_rn(a) | (bf16_rn(b) << 16);
}
__device__ __forceinline__ float2 up2(unsigned u) {
    return make_float2(__uint_as_float(u << 16),
                       __uint_as_float(u & 0xFFFF0000u));
}

__device__ __forceinline__ float2 f2add(float2 a, float2 b) {
    return make_float2(a.x + b.x, a.y + b.y);
}
__device__ __forceinline__ float2 f2sub(float2 a, float2 b) {
    return make_float2(a.x - b.x, a.y - b.y);
}

// ---------------------------------------------------------------------------
// K1: vertical 61-tap box-sum of x -> V1 (bf16-packed). float2 columns,
// VSEGH=32 rows/seg, 1024 blocks (4 blocks/CU -> 16 waves/CU).
__global__ __launch_bounds__(256, 2) void vbox_kernel(const float* __restrict__ in,
                                                      unsigned* __restrict__ out) {
    int tid = blockIdx.x * 256 + threadIdx.x;
    int col = tid & (NCOL2 - 1);
    int seg = tid >> 13;
    int n = col >> 10;
    int w2 = col & (STR2 - 1);
    const float2* ip = (const float2*)(in + (size_t)n * IMGSZ) + w2;
    unsigned* op = out + (size_t)n * (IMGSZ / 2) + w2;
    int h0 = seg * VSEGH;
    float2 S = make_float2(0.f, 0.f);
    int lo = h0 - RAD; if (lo < 0) lo = 0;
    int h = lo;
    for (; h + 8 <= h0 + RAD; h += 8) {
        float2 W[8];
        #pragma unroll
        for (int i = 0; i < 8; ++i) W[i] = ip[(h + i) * STR2];
        __builtin_amdgcn_sched_barrier(0);
        #pragma unroll
        for (int i = 0; i < 8; ++i) S = f2add(S, W[i]);
    }
    for (; h < h0 + RAD; ++h) S = f2add(S, ip[h * STR2]);

    if (seg != 0 && seg != VNSEG - 1) {
        const float2* lp = ip + (h0 + RAD) * STR2;
        const float2* tp = ip + (h0 - RAD) * STR2;
        unsigned* opp = op + (size_t)h0 * STR2;
        for (int r = 0; r < VSEGH; r += 8) {
            float2 L[8], T[8];
            #pragma unroll
            for (int i = 0; i < 8; ++i) L[i] = lp[(r + i) * STR2];
            #pragma unroll
            for (int i = 0; i < 8; ++i) T[i] = tp[(r + i) * STR2];
            __builtin_amdgcn_sched_barrier(0);
            #pragma unroll
            for (int i = 0; i < 8; ++i) {
                S = f2add(S, L[i]);
                opp[(r + i) * STR2] = pk2(S.x, S.y);
                S = f2sub(S, T[i]);
            }
        }
    } else {
        const float2 Z = make_float2(0.f, 0.f);
        for (int ho = h0; ho < h0 + VSEGH; ho += 4) {
            float2 a[4], b[4];
            #pragma unroll
            for (int i = 0; i < 4; ++i) {
                int ha = ho + i + RAD;
                a[i] = (ha < HH) ? ip[ha * STR2] : Z;
            }
            #pragma unroll
            for (int i = 0; i < 4; ++i) {
                int hb = ho + i - RAD;
                b[i] = (hb >= 0) ? ip[hb * STR2] : Z;
            }
            #pragma unroll
            for (int i = 0; i < 4; ++i) {
                S = f2add(S, a[i]);
                op[(size_t)(ho + i) * STR2] = pk2(S.x, S.y);
                S = f2sub(S, b[i]);
            }
        }
    }
}

__device__ inline float wave_incl_scan(float v) {
    int lane = threadIdx.x & 63;
    #pragma unroll
    for (int d = 1; d < 64; d <<= 1) {
        float o = __shfl_up(v, d, 64);
        if (lane >= d) v += o;
    }
    return v;
}

// ---------------------------------------------------------------------------
// K2': fused middle kernel, one block per row.
//   phase 1: prefix-scan V1 row -> horizontal box -> m; out = x - m (fp32)
//   phase 2: prefix-scan out and out^2 rows (still in LDS) -> 61-tap horizontal
//            box sums, written INTERLEAVED as uint2{h1,h2} per pixel (bf16x2 each).
__global__ __launch_bounds__(256) void hmid_kernel(const unsigned* __restrict__ vsum,
                                                   const float* __restrict__ x,
                                                   float* __restrict__ out,
                                                   uint2* __restrict__ hig) {
    __shared__ float ch[2][PDW];     // V1 per-channel prefix
    __shared__ float s4[4][PDW];     // [0..1]=out ch0/1, [2..3]=out^2 ch0/1
    __shared__ float wtot[4];
    int t = threadIdx.x;
    size_t g = (size_t)blockIdx.x * ROWSZ;
    const uint4* vrow = (const uint4*)(vsum + (size_t)blockIdx.x * STR2);
    uint4 u = vrow[t];   // 4 pixels x 2 ch
    {
        float2 p0 = up2(u.x), p1 = up2(u.y), p2 = up2(u.z), p3 = up2(u.w);
        int w = 4 * t;
        ch[0][PD(w + 0)] = p0.x; ch[1][PD(w + 0)] = p0.y;
        ch[0][PD(w + 1)] = p1.x; ch[1][PD(w + 1)] = p1.y;
        ch[0][PD(w + 2)] = p2.x; ch[1][PD(w + 2)] = p2.y;
        ch[0][PD(w + 3)] = p3.x; ch[1][PD(w + 3)] = p3.y;
    }
    __syncthreads();
    // prefix: 2 waves per channel, per-thread chunk of 8
    {
        int c = t >> 7, j = t & 127, base = j * 8;
        float v[8]; float run = 0.f;
        #pragma unroll
        for (int i = 0; i < 8; ++i) { run += ch[c][PD(base + i)]; v[i] = run; }
        float incl = wave_incl_scan(run);
        int wid = t >> 6;
        if ((t & 63) == 63) wtot[wid] = incl;
        __syncthreads();
        float off = incl - run;
        if (wid & 1) off += wtot[wid - 1];
        #pragma unroll
        for (int i = 0; i < 8; ++i) ch[c][PD(base + i)] = off + v[i];
    }
    __syncthreads();
    const float4* xrow = (const float4*)(x + g);
    float4* orow = (float4*)(out + g);
    #pragma unroll
    for (int i = 0; i < 2; ++i) {
        int jj = t + 256 * i;
        int w0 = 2 * jj, w1 = 2 * jj + 1;
        int hi0 = w0 + RAD; if (hi0 > WW - 1) hi0 = WW - 1;
        int hi1 = w1 + RAD; if (hi1 > WW - 1) hi1 = WW - 1;
        int lo0 = w0 - RAD - 1, lo1 = w1 - RAD - 1;
        float s00 = ch[0][PD(hi0)], s10 = ch[1][PD(hi0)];
        if (lo0 >= 0) { s00 -= ch[0][PD(lo0)]; s10 -= ch[1][PD(lo0)]; }
        float s01 = ch[0][PD(hi1)], s11 = ch[1][PD(hi1)];
        if (lo1 >= 0) { s01 -= ch[0][PD(lo1)]; s11 -= ch[1][PD(lo1)]; }
        float4 xv = xrow[jj];
        float4 o;
        o.x = xv.x - SCALEV * s00; o.y = xv.y - SCALEV * s10;
        o.z = xv.z - SCALEV * s01; o.w = xv.w - SCALEV * s11;
        orow[jj] = o;
        s4[0][PD(w0)] = o.x;       s4[1][PD(w0)] = o.y;
        s4[0][PD(w1)] = o.z;       s4[1][PD(w1)] = o.w;
        s4[2][PD(w0)] = o.x * o.x; s4[3][PD(w0)] = o.y * o.y;
        s4[2][PD(w1)] = o.z * o.z; s4[3][PD(w1)] = o.w * o.w;
    }
    __syncthreads();
    // prefix: 4 arrays, 1 wave each, chunk 16
    {
        int a = t >> 6, j = t & 63, base = j * 16;
        float v[16]; float run = 0.f;
        #pragma unroll
        for (int i = 0; i < 16; ++i) { run += s4[a][PD(base + i)]; v[i] = run; }
        float incl = wave_incl_scan(run);
        float off = incl - run;
        #pragma unroll
        for (int i = 0; i < 16; ++i) s4[a][PD(base + i)] = off + v[i];
    }
    __syncthreads();
    uint4* hirow = (uint4*)(hig + (size_t)blockIdx.x * STR2);
    #pragma unroll
    for (int i = 0; i < 2; ++i) {
        int jj = t + 256 * i;
        int w0 = 2 * jj, w1 = 2 * jj + 1;
        int hi0 = w0 + RAD; if (hi0 > WW - 1) hi0 = WW - 1;
        int hi1 = w1 + RAD; if (hi1 > WW - 1) hi1 = WW - 1;
        int lo0 = w0 - RAD - 1, lo1 = w1 - RAD - 1;
        float a00 = s4[0][PD(hi0)], a10 = s4[1][PD(hi0)];
        float q00 = s4[2][PD(hi0)], q10 = s4[3][PD(hi0)];
        if (lo0 >= 0) {
            a00 -= s4[0][PD(lo0)]; a10 -= s4[1][PD(lo0)];
            q00 -= s4[2][PD(lo0)]; q10 -= s4[3][PD(lo0)];
        }
        float a01 = s4[0][PD(hi1)], a11 = s4[1][PD(hi1)];
        float q01 = s4[2][PD(hi1)], q11 = s4[3][PD(hi1)];
        if (lo1 >= 0) {
            a01 -= s4[0][PD(lo1)]; a11 -= s4[1][PD(lo1)];
            q01 -= s4[2][PD(lo1)]; q11 -= s4[3][PD(lo1)];
        }
        // interleaved: per pixel uint2{ pk2(h1 ch0,ch1), pk2(h2 ch0,ch1) }
        hirow[jj] = make_uint4(pk2(a00, a10), pk2(q00, q10),
                               pk2(a01, a11), pk2(q01, q11));
    }
}

// ---------------------------------------------------------------------------
// K3': vertical 61-box of interleaved HI (bf16 in) + finalize
// y = out/(sqrt(var)+eps), in place on the out buffer.
__global__ __launch_bounds__(256, 2) void vfinal_kernel(const uint2* __restrict__ hi,
                                                        float* __restrict__ io) {
    int tid = blockIdx.x * 256 + threadIdx.x;
    int col = tid & (NCOL2 - 1);
    int seg = tid >> 13;
    int n = col >> 10;
    int w2 = col & (STR2 - 1);
    const uint2* pp = hi + (size_t)n * ((size_t)HH * STR2) + w2;
    float2* op = (float2*)(io + (size_t)n * IMGSZ) + w2;
    int h0 = seg * VSEGH;
    float2 S1 = make_float2(0.f, 0.f);
    float2 S2 = make_float2(0.f, 0.f);
    int lo = h0 - RAD; if (lo < 0) lo = 0;
    int h = lo;
    for (; h + 8 <= h0 + RAD; h += 8) {
        uint2 A[8];
        #pragma unroll
        for (int i = 0; i < 8; ++i) A[i] = pp[(h + i) * STR2];
        __builtin_amdgcn_sched_barrier(0);
        #pragma unroll
        for (int i = 0; i < 8; ++i) {
            S1 = f2add(S1, up2(A[i].x));
            S2 = f2add(S2, up2(A[i].y));
        }
    }
    for (; h < h0 + RAD; ++h) {
        uint2 v = pp[h * STR2];
        S1 = f2add(S1, up2(v.x));
        S2 = f2add(S2, up2(v.y));
    }

    if (seg != 0 && seg != VNSEG - 1) {
        const uint2* lp = pp + (h0 + RAD) * STR2;
        const uint2* tp = pp + (h0 - RAD) * STR2;
        float2* q = op + (size_t)h0 * STR2;
        for (int r = 0; r < VSEGH; r += 8) {
            uint2 L[8], T[8];
            float2 O[8];
            #pragma unroll
            for (int i = 0; i < 8; ++i) L[i] = lp[(r + i) * STR2];
            #pragma unroll
            for (int i = 0; i < 8; ++i) T[i] = tp[(r + i) * STR2];
            #pragma unroll
            for (int i = 0; i < 8; ++i) O[i] = q[(r + i) * STR2];
            __builtin_amdgcn_sched_barrier(0);
            #pragma unroll
            for (int i = 0; i < 8; ++i) {
                S1 = f2add(S1, up2(L[i].x));
                S2 = f2add(S2, up2(L[i].y));
                float c1x = SCALEV * S1.x, c1y = SCALEV * S1.y;
                float vx = fmaxf(SCALEV * S2.x - c1x * c1x, 0.f);
                float vy = fmaxf(SCALEV * S2.y - c1y * c1y, 0.f);
                float2 yv;
                yv.x = O[i].x / (sqrtf(vx) + EPSV);
                yv.y = O[i].y / (sqrtf(vy) + EPSV);
                q[(r + i) * STR2] = yv;
                S1 = f2sub(S1, up2(T[i].x));
                S2 = f2sub(S2, up2(T[i].y));
            }
        }
    } else {
        const uint2 Z2u = make_uint2(0u, 0u);
        for (int ho = h0; ho < h0 + VSEGH; ho += 4) {
            uint2 a[4], b[4];
            float2 O[4];
            #pragma unroll
            for (int i = 0; i < 4; ++i) {
                int ha = ho + i + RAD;
                a[i] = (ha < HH) ? pp[ha * STR2] : Z2u;
            }
            #pragma unroll
            for (int i = 0; i < 4; ++i) {
                int hb = ho + i - RAD;
                b[i] = (hb >= 0) ? pp[hb * STR2] : Z2u;
            }
            #pragma unroll
            for (int i = 0; i < 4; ++i) O[i] = op[(size_t)(ho + i) * STR2];
            #pragma unroll
            for (int i = 0; i < 4; ++i) {
                S1 = f2add(S1, up2(a[i].x));
                S2 = f2add(S2, up2(a[i].y));
                float c1x = SCALEV * S1.x, c1y = SCALEV * S1.y;
                float vx = fmaxf(SCALEV * S2.x - c1x * c1x, 0.f);
                float vy = fmaxf(SCALEV * S2.y - c1y * c1y, 0.f);
                float2 yv;
                yv.x = O[i].x / (sqrtf(vx) + EPSV);
                yv.y = O[i].y / (sqrtf(vy) + EPSV);
                op[(size_t)(ho + i) * STR2] = yv;
                S1 = f2sub(S1, up2(b[i].x));
                S2 = f2sub(S2, up2(b[i].y));
            }
        }
    }
}

extern "C" void kernel_launch(void* const* d_in, const int* in_sizes, int n_in,
                              void* d_out, int out_size, void* d_ws, size_t ws_size,
                              hipStream_t stream) {
    const float* x = (const float*)d_in[0];
    float* out = (float*)d_out;
    unsigned* V1 = (unsigned*)d_ws;                       // 32 MB bf16 vbox(x)
    uint2* HI = (uint2*)(V1 + (size_t)NB * IMGSZ / 2);    // 64 MB interleaved Hbox(out), Hbox(out^2)

    int vgrid = (NCOL2 * VNSEG) / 256;                    // 1024 blocks
    vbox_kernel<<<vgrid, 256, 0, stream>>>(x, V1);
    hmid_kernel<<<NB * HH, 256, 0, stream>>>(V1, x, out, HI);
    vfinal_kernel<<<vgrid, 256, 0, stream>>>(HI, out);
}